// Round 2
// baseline (142.178 us; speedup 1.0000x reference)
//
#include <hip/hip_runtime.h>

// ---------------- Kernel 1: g/phi convs + 2x2 maxpool + kv outer-product accumulate ----------------
// grid = B*32 (one block per batch per pooled row), block = 256
__global__ __launch_bounds__(256) void k1_kv(const float* __restrict__ x,
    const float* __restrict__ w1, const float* __restrict__ b1,
    const float* __restrict__ w22, const float* __restrict__ b22,
    float* __restrict__ kv)
{
  __shared__ float xl[64][128];    // [ch][h2*64+w] two image rows
  __shared__ float wlt[64][64];    // [ch][o]  o<32: w1, o>=32: w22 (transposed)
  __shared__ float bl[64];
  __shared__ float phil[32][33];   // [i][p]  (padded)
  __shared__ float glt[32][33];    // [p][j]  (padded)
  int t = threadIdx.x;
  int b = blockIdx.x >> 5, r = blockIdx.x & 31;
  const float* xb = x + ((size_t)b << 18);

  for (int v = t; v < 2048; v += 256) {            // 64ch * 2rows * 64px / 4
    int c = v >> 5, rem = v & 31;
    int h2 = rem >> 4, wv = rem & 15;
    float4 u = *(const float4*)(xb + c*4096 + (2*r + h2)*64 + wv*4);
    float* dst = &xl[c][h2*64 + wv*4];
    dst[0] = u.x; dst[1] = u.y; dst[2] = u.z; dst[3] = u.w;
  }
  for (int v = t; v < 1024; v += 256) {            // w1 (512 vecs) + w22 (512 vecs)
    int half = v >> 9, vv = v & 511;
    int o = vv >> 4;                               // 0..31
    int cb = (vv & 15) * 4;
    const float* src = (half ? w22 : w1) + o*64 + cb;
    float4 u = *(const float4*)src;
    int oo = o + half*32;
    wlt[cb+0][oo] = u.x; wlt[cb+1][oo] = u.y; wlt[cb+2][oo] = u.z; wlt[cb+3][oo] = u.w;
  }
  if (t < 32) bl[t] = b1[t];
  else if (t < 64) bl[t] = b22[t-32];
  __syncthreads();

  int p = t & 31, og = t >> 5;                     // pooled col, output group (8 groups of 4)
  float acc0[4][4], acc1[4][4];                    // [k][pix]
  #pragma unroll
  for (int k = 0; k < 4; k++)
    #pragma unroll
    for (int px = 0; px < 4; px++) { acc0[k][px] = 0.f; acc1[k][px] = 0.f; }

  #pragma unroll 4
  for (int c = 0; c < 64; c++) {
    float2 x0 = *(const float2*)&xl[c][2*p];       // row h2=0, w=2p,2p+1
    float2 x1 = *(const float2*)&xl[c][64 + 2*p];  // row h2=1
    float4 wa = *(const float4*)&wlt[c][og*4];     // w1 outputs
    float4 wb = *(const float4*)&wlt[c][32 + og*4];// w22 outputs
    float xs[4]  = {x0.x, x0.y, x1.x, x1.y};
    float was[4] = {wa.x, wa.y, wa.z, wa.w};
    float wbs[4] = {wb.x, wb.y, wb.z, wb.w};
    #pragma unroll
    for (int k = 0; k < 4; k++)
      #pragma unroll
      for (int px = 0; px < 4; px++) {
        acc0[k][px] += was[k] * xs[px];
        acc1[k][px] += wbs[k] * xs[px];
      }
  }
  #pragma unroll
  for (int k = 0; k < 4; k++) {
    int o = og*4 + k;
    float m1 = fmaxf(fmaxf(acc0[k][0], acc0[k][1]), fmaxf(acc0[k][2], acc0[k][3])) + bl[o];
    float m2 = fmaxf(fmaxf(acc1[k][0], acc1[k][1]), fmaxf(acc1[k][2], acc1[k][3])) + bl[32+o];
    glt[p][o]  = m1;   // g   = maxpool(conv1(x,w1,b1))
    phil[o][p] = m2;   // phi = maxpool(conv1x1(x,w22,b22))
  }
  __syncthreads();

  float* kvb = kv + b*1024;
  for (int e = t; e < 1024; e += 256) {            // kv[i][j] += sum_p phi[i,p]*g[j,p]
    int i = e >> 5, j = e & 31;
    float s = 0.f;
    #pragma unroll
    for (int q = 0; q < 32; q++) s += phil[i][q] * glt[q][j];
    atomicAdd(&kvb[e], s);
  }
}

// ---------------- Kernel 2: per-batch W[b] = (w3 @ (kv/N)^T) @ w21, bias[b] ----------------
// grid = B, block = 64 (thread = output channel c)
__global__ __launch_bounds__(64) void k2_wmat(const float* __restrict__ kv,
    const float* __restrict__ w3, const float* __restrict__ b3,
    const float* __restrict__ w21, const float* __restrict__ b21,
    float* __restrict__ Wm, float* __restrict__ biasv)
{
  __shared__ float kvl[32][32];
  __shared__ float w3t[32][64];    // [j][c]
  __shared__ float w21l[32][64];   // [i][ch]
  __shared__ float b21l[32];
  int t = threadIdx.x, b = blockIdx.x;
  for (int e = t; e < 1024; e += 64) kvl[e>>5][e&31] = kv[b*1024 + e] * (1.f/1024.f);
  for (int e = t; e < 2048; e += 64) { int c = e >> 5, j = e & 31; w3t[j][c] = w3[e]; }
  for (int e = t; e < 2048; e += 64) { int i = e >> 6, ch = e & 63; w21l[i][ch] = w21[e]; }
  if (t < 32) b21l[t] = b21[t];
  __syncthreads();

  int c = t;
  float A[32];                                     // A[c][i] = sum_j w3[c,j]*kv[i,j]/N
  #pragma unroll
  for (int i = 0; i < 32; i++) {
    float s = 0.f;
    #pragma unroll
    for (int j = 0; j < 32; j++) s += w3t[j][c] * kvl[i][j];
    A[i] = s;
  }
  float bias = b3[c];
  #pragma unroll
  for (int i = 0; i < 32; i++) bias += A[i] * b21l[i];
  biasv[b*64 + c] = bias;
  float* Wrow = Wm + (b*64 + c)*64;
  #pragma unroll
  for (int ch = 0; ch < 64; ch++) {
    float s = 0.f;
    #pragma unroll
    for (int i = 0; i < 32; i++) s += A[i] * w21l[i][ch];
    Wrow[ch] = s;
  }
}

// ---------------- Kernel 3: z = W[b]@x + bias, per-block partial BN stats (z discarded) ------------
// grid = B*32tiles*4cgroups = 2048, block = 128 (thread = pixel; block owns 16 channels)
__global__ __launch_bounds__(128) void k3_stats(const float* __restrict__ x,
    const float* __restrict__ Wm, const float* __restrict__ biasv,
    float* __restrict__ part)
{
  __shared__ float xt[64][128];
  __shared__ float lstat[32];
  int t = threadIdx.x, blk = blockIdx.x;
  int cg = blk & 3, tile = (blk >> 2) & 31, b = blk >> 7;
  const float* xb = x + ((size_t)b << 18) + tile*128;
  for (int v = t; v < 2048; v += 128) {
    int ch = v >> 5, rem = v & 31;
    float4 u = *(const float4*)(xb + ch*4096 + rem*4);
    float* dst = &xt[ch][rem*4];
    dst[0] = u.x; dst[1] = u.y; dst[2] = u.z; dst[3] = u.w;
  }
  if (t < 32) lstat[t] = 0.f;
  __syncthreads();
  float xr[64];
  #pragma unroll
  for (int ch = 0; ch < 64; ch++) xr[ch] = xt[ch][t];
  const float* Wb = Wm + (b*64 + cg*16)*64;        // wave-uniform -> scalar loads
  const float* bv = biasv + b*64 + cg*16;
  int lane = t & 63;
  #pragma unroll
  for (int q = 0; q < 16; q++) {
    float acc = bv[q];
    const float* wr = Wb + q*64;
    #pragma unroll
    for (int ch = 0; ch < 64; ch++) acc += wr[ch] * xr[ch];
    float v1 = acc, v2 = acc*acc;
    #pragma unroll
    for (int off = 32; off > 0; off >>= 1) { v1 += __shfl_down(v1, off); v2 += __shfl_down(v2, off); }
    if (lane == 0) { atomicAdd(&lstat[q], v1); atomicAdd(&lstat[16+q], v2); }
  }
  __syncthreads();
  if (t < 32) part[blk*32 + t] = lstat[t];         // [0:16)=sum, [16:32)=sumsq for c=cg*16+q
}

// ---------------- Kernel 3r: reduce 512 (b,tile) partials per (c,stat) ----------------
__global__ __launch_bounds__(128) void k3_reduce(const float* __restrict__ part, float* __restrict__ stats)
{
  int t = threadIdx.x;
  int c = t & 63, which = t >> 6;                  // 0=sum, 1=sumsq
  int cg = c >> 4, q = c & 15;
  float s = 0.f;
  for (int m = 0; m < 512; m++) s += part[(m*4 + cg)*32 + which*16 + q];
  stats[t] = s;                                    // stats[c]=sum, stats[64+c]=sumsq
}

// ---------------- Kernel 4: recompute z, batchnorm, + x, write fp32 ----------------
__global__ __launch_bounds__(128) void k4_out(const float* __restrict__ x,
    const float* __restrict__ Wm, const float* __restrict__ biasv,
    const float* __restrict__ stats,
    const float* __restrict__ gamma, const float* __restrict__ beta,
    float* __restrict__ out)
{
  __shared__ float xt[64][128];
  int t = threadIdx.x, blk = blockIdx.x;
  int cg = blk & 3, tile = (blk >> 2) & 31, b = blk >> 7;
  const float* xb = x + ((size_t)b << 18) + tile*128;
  for (int v = t; v < 2048; v += 128) {
    int ch = v >> 5, rem = v & 31;
    float4 u = *(const float4*)(xb + ch*4096 + rem*4);
    float* dst = &xt[ch][rem*4];
    dst[0] = u.x; dst[1] = u.y; dst[2] = u.z; dst[3] = u.w;
  }
  __syncthreads();
  float xr[64];
  #pragma unroll
  for (int ch = 0; ch < 64; ch++) xr[ch] = xt[ch][t];
  const float* Wb = Wm + (b*64 + cg*16)*64;
  const float* bv = biasv + b*64 + cg*16;
  const float inv_cnt = 1.f / 65536.f;             // B*HW
  size_t obase = ((size_t)b << 18) + (size_t)(cg*16)*4096 + (size_t)tile*128 + t;
  #pragma unroll
  for (int q = 0; q < 16; q++) {
    int c = cg*16 + q;
    float acc = bv[q];
    const float* wr = Wb + q*64;
    #pragma unroll
    for (int ch = 0; ch < 64; ch++) acc += wr[ch] * xr[ch];
    float mu  = stats[c] * inv_cnt;
    float var = stats[64+c] * inv_cnt - mu*mu;
    float sc  = gamma[c] * rsqrtf(var + 1e-5f);
    float val = sc * (acc - mu) + beta[c] + xr[c];
    out[obase + (size_t)q*4096] = val;
  }
}

extern "C" void kernel_launch(void* const* d_in, const int* in_sizes, int n_in,
                              void* d_out, int out_size, void* d_ws, size_t ws_size,
                              hipStream_t stream)
{
  const float* x    = (const float*)d_in[0];
  const float* w1   = (const float*)d_in[1];
  const float* b1   = (const float*)d_in[2];
  const float* w21  = (const float*)d_in[3];
  const float* b21  = (const float*)d_in[4];
  const float* w22  = (const float*)d_in[5];
  const float* b22  = (const float*)d_in[6];
  const float* w3   = (const float*)d_in[7];
  const float* b3   = (const float*)d_in[8];
  const float* gamma= (const float*)d_in[9];
  const float* beta = (const float*)d_in[10];

  float* ws    = (float*)d_ws;
  float* kv    = ws;              // 16384
  float* Wm    = ws + 16384;      // 65536 floats (1024 used per batch row-major 64x64)
  float* biasv = ws + 81920;      // 1024
  float* part  = ws + 82944;      // 65536
  float* stats = ws + 148480;     // 128

  hipMemsetAsync(kv, 0, 16384 * sizeof(float), stream);
  hipLaunchKernelGGL(k1_kv,     dim3(512),  dim3(256), 0, stream, x, w1, b1, w22, b22, kv);
  hipLaunchKernelGGL(k2_wmat,   dim3(16),   dim3(64),  0, stream, kv, w3, b3, w21, b21, Wm, biasv);
  hipLaunchKernelGGL(k3_stats,  dim3(2048), dim3(128), 0, stream, x, Wm, biasv, part);
  hipLaunchKernelGGL(k3_reduce, dim3(1),    dim3(128), 0, stream, part, stats);
  hipLaunchKernelGGL(k4_out,    dim3(2048), dim3(128), 0, stream, x, Wm, biasv, stats, gamma, beta,
                     (float*)d_out);
}